// Round 13
// baseline (1526.133 us; speedup 1.0000x reference)
//
#include <hip/hip_runtime.h>
#include <stdint.h>

#define LAYERS 4
#define BATCH  32
#define SEQT   128
#define HID    1024
#define VOCAB  32000

typedef __attribute__((ext_vector_type(8))) short short8;
typedef __attribute__((ext_vector_type(8))) __bf16 bf16x8;
typedef __attribute__((ext_vector_type(4))) float floatx4;

// ws layout (bytes)
#define CLS_OFF  0ul           // 32000*1024*2  = 65,536,000
#define X_OFF    65536000ul    // 128*32*1024*2 =  8,388,608
#define RES_OFF  73924608ul    // 4*128*32*1024*2 = 33,554,432
#define HBT_OFF  107479040ul   // 129*4*32*1024*2 = 33,816,576 (time-indexed h)
#define CF_OFF   141295616ul   // 4*32*1024*4   = 524,288
#define SYNC_OFF 141819904ul   // flags[l][wg] u32 CONTIGUOUS at l*64+wg; acquire word @2048

#define LOGITS_N 131072000ul
#define BH (BATCH * HID)

__device__ __forceinline__ unsigned short f2bf(float f) {
  union { float f; unsigned u; } v; v.f = f;
  unsigned r = v.u + 0x7FFF + ((v.u >> 16) & 1);
  return (unsigned short)(r >> 16);
}
__device__ __forceinline__ float bf2f(unsigned short b) {
  union { unsigned u; float f; } v; v.u = ((unsigned)b) << 16;
  return v.f;
}
__device__ __forceinline__ floatx4 mfma16(short8 a, short8 b, floatx4 c) {
  return __builtin_amdgcn_mfma_f32_16x16x32_bf16(
      __builtin_bit_cast(bf16x8, a), __builtin_bit_cast(bf16x8, b), c, 0, 0, 0);
}
__device__ __forceinline__ short8 cvt8(float4 a, float4 b) {
  short8 r;
  r[0] = (short)f2bf(a.x); r[1] = (short)f2bf(a.y);
  r[2] = (short)f2bf(a.z); r[3] = (short)f2bf(a.w);
  r[4] = (short)f2bf(b.x); r[5] = (short)f2bf(b.y);
  r[6] = (short)f2bf(b.z); r[7] = (short)f2bf(b.w);
  return r;
}

// ---------------- prep kernels ----------------

__global__ void k_convert(const float* __restrict__ clsw, unsigned short* __restrict__ oC) {
  const long long NC4 = 8192000LL;   // V*H/4
  for (long long i = (long long)blockIdx.x * blockDim.x + threadIdx.x; i < NC4;
       i += (long long)gridDim.x * blockDim.x) {
    float4 v = *(const float4*)(clsw + (i << 2));
    ushort4 o; o.x = f2bf(v.x); o.y = f2bf(v.y); o.z = f2bf(v.z); o.w = f2bf(v.w);
    *(ushort4*)(oC + (i << 2)) = o;
  }
}

__global__ void k_embed(const int* __restrict__ tok, const float* __restrict__ emb,
                        unsigned short* __restrict__ X) {
  const int bt = blockIdx.x;            // t*32 + b
  const int t = bt >> 5, b = bt & 31;
  const int v = tok[b * SEQT + t];      // dec_input is [B,T]
  const float4* src = (const float4*)(emb + (size_t)v * HID);
  ushort4* dst = (ushort4*)(X + (size_t)bt * HID);
  const int i = threadIdx.x;
  float4 f = src[i];
  ushort4 o; o.x = f2bf(f.x); o.y = f2bf(f.y); o.z = f2bf(f.z); o.w = f2bf(f.w);
  dst[i] = o;
}

__global__ void k_init(const float* __restrict__ h0, const float* __restrict__ c0,
                       unsigned short* __restrict__ HBT, float* __restrict__ CF,
                       unsigned* __restrict__ sync) {
  const int i = blockIdx.x * blockDim.x + threadIdx.x;
  if (i < 4096) sync[i] = 0u;
  if (i < LAYERS * BATCH * HID) {
    HBT[i] = f2bf(h0[i]);   // HBT[t=0][l][b][h] == h0 layout
    CF[i] = c0[i];
  }
}

// ---------------- persistent LSTM (r7 structure, merged gate + single load block) --------
// 256 wgs x 512 threads (cooperative), 1 wg/CU. p -> (l=(p&7)>>1, jj): layer on an
// XCD pair. Weights in registers. CONTIGUOUS per-wg epoch flags (4-line poll sweep).
// Both dependencies (x: layer l-1 @ t, h: own layer @ t-1) land at the same wall
// step, so one merged wave0 poll + ONE 17-load asm block with a single vmcnt(0)
// (removes a serialized MALL round-trip vs split x/h phases). Data write-through;
// reads cached (write-once addresses); one agent-acquire at start for replays.

__global__ __launch_bounds__(512, 2) void k_lstm(
    const float* __restrict__ Wih, const float* __restrict__ Whh,
    const float* __restrict__ bih, const float* __restrict__ bhh,
    const unsigned short* __restrict__ X, unsigned short* __restrict__ RES,
    unsigned short* __restrict__ HBT, const float* __restrict__ CF,
    float* __restrict__ out, unsigned* __restrict__ syncp) {
  const int p = blockIdx.x;
  const int l = (p & 7) >> 1;                       // XCD pair {2l,2l+1}
  const int jj = ((p >> 3) << 1) | (p & 1);         // 0..63 within layer
  const int j0 = jj << 4;
  const int tid = threadIdx.x;
  const int q = tid >> 6;                 // wave 0..7 -> K slice q*128
  const int lane = tid & 63;
  const int lo = lane & 15, hi = lane >> 4;
  const int u = tid & 15, b = tid >> 4;   // cell mapping: unit u (fast), batch b

  __shared__ float red[8][32][66];        // split-K reduce, padded
  __shared__ unsigned mbx;                // LDS mailbox

  if (tid == 0) mbx = 0u;

  // one-time acquire: invalidate L1/L2 (stale lines from prior replay / poison)
  (void)__hip_atomic_load(syncp + 2048, __ATOMIC_ACQUIRE, __HIP_MEMORY_SCOPE_AGENT);

  const unsigned* fx = syncp + ((l - 1) & 3) * 64 + lane;   // contiguous flags
  const unsigned* fh = syncp + l * 64 + lane;
  unsigned* fown = syncp + l * 64 + jj;

  // ---- one-time: weights f32 -> bf16 fragments in registers ----
  short8 wx[4][4], wh[4][4];              // [gate][ks], 128 regs
  {
    const size_t lb = (size_t)l * 4096;
#pragma unroll
    for (int ct = 0; ct < 4; ++ct) {
#pragma unroll
      for (int ks = 0; ks < 4; ++ks) {
        const size_t off = (lb + (size_t)(ct * 1024 + j0 + lo)) * HID
                         + (size_t)q * 128 + ks * 32 + hi * 8;
        float4 a0 = *(const float4*)(Wih + off);
        float4 a1 = *(const float4*)(Wih + off + 4);
        wx[ct][ks] = cvt8(a0, a1);
        float4 b0 = *(const float4*)(Whh + off);
        float4 b1 = *(const float4*)(Whh + off + 4);
        wh[ct][ks] = cvt8(b0, b1);
      }
    }
  }
  float bias_g[4];
#pragma unroll
  for (int g = 0; g < 4; ++g)
    bias_g[g] = bih[l * 4096 + g * 1024 + j0 + u] + bhh[l * 4096 + g * 1024 + j0 + u];
  float c_reg = CF[(size_t)l * BH + (size_t)b * HID + j0 + u];

  __syncthreads();   // mailbox init visible

  for (int t = 0; t < SEQT; ++t) {
    // ---- merged gate: wave0 polls BOTH flags, others spin LDS mailbox ----
    if (q == 0) {
      if (l > 0 || t > 0) {
        for (;;) {
          int ok = 1;
          if (l > 0)
            ok &= (__hip_atomic_load(fx, __ATOMIC_RELAXED, __HIP_MEMORY_SCOPE_AGENT)
                   >= (unsigned)(t + 1));
          if (t > 0)
            ok &= (__hip_atomic_load(fh, __ATOMIC_RELAXED, __HIP_MEMORY_SCOPE_AGENT)
                   >= (unsigned)t);
          if (__all(ok)) break;
          __builtin_amdgcn_s_sleep(1);
        }
      }
      __hip_atomic_store(&mbx, (unsigned)(t + 1),
                         __ATOMIC_RELAXED, __HIP_MEMORY_SCOPE_WORKGROUP);
    } else {
      while (__hip_atomic_load(&mbx, __ATOMIC_RELAXED, __HIP_MEMORY_SCOPE_WORKGROUP)
             < (unsigned)(t + 1))
        __builtin_amdgcn_s_sleep(1);
    }

    const unsigned short* xsrc = (l == 0)
        ? (X + (size_t)t * BH)
        : (RES + ((size_t)(l - 1) * SEQT + t) * BH);
    const unsigned short* hsrc = HBT + ((size_t)t * LAYERS + l) * BH;

    // MFMA A-fragment: lane (lo,hi) holds k = q*128 + ks*32 + hi*8 + [0,8)
    const unsigned short* px0 = xsrc + (size_t)lo * HID + q * 128 + hi * 8;
    const unsigned short* px1 = px0 + 16 * HID;
    const unsigned short* ph0 = hsrc + (size_t)lo * HID + q * 128 + hi * 8;
    const unsigned short* ph1 = ph0 + 16 * HID;
    const unsigned short* pxr = xsrc + (size_t)b * HID + j0 + u;

    short8 x0a, x0b, x0c, x0d, x1a, x1b, x1c, x1d;
    short8 h0a, h0b, h0c, h0d, h1a, h1b, h1c, h1d;
    unsigned xres;
    asm volatile(
      "global_load_dwordx4 %0,  %17, off\n\t"
      "global_load_dwordx4 %1,  %17, off offset:64\n\t"
      "global_load_dwordx4 %2,  %17, off offset:128\n\t"
      "global_load_dwordx4 %3,  %17, off offset:192\n\t"
      "global_load_dwordx4 %4,  %18, off\n\t"
      "global_load_dwordx4 %5,  %18, off offset:64\n\t"
      "global_load_dwordx4 %6,  %18, off offset:128\n\t"
      "global_load_dwordx4 %7,  %18, off offset:192\n\t"
      "global_load_dwordx4 %8,  %19, off\n\t"
      "global_load_dwordx4 %9,  %19, off offset:64\n\t"
      "global_load_dwordx4 %10, %19, off offset:128\n\t"
      "global_load_dwordx4 %11, %19, off offset:192\n\t"
      "global_load_dwordx4 %12, %20, off\n\t"
      "global_load_dwordx4 %13, %20, off offset:64\n\t"
      "global_load_dwordx4 %14, %20, off offset:128\n\t"
      "global_load_dwordx4 %15, %20, off offset:192\n\t"
      "global_load_ushort  %16, %21, off\n\t"
      "s_waitcnt vmcnt(0)"
      : "=&v"(x0a), "=&v"(x0b), "=&v"(x0c), "=&v"(x0d),
        "=&v"(x1a), "=&v"(x1b), "=&v"(x1c), "=&v"(x1d),
        "=&v"(h0a), "=&v"(h0b), "=&v"(h0c), "=&v"(h0d),
        "=&v"(h1a), "=&v"(h1b), "=&v"(h1c), "=&v"(h1d),
        "=&v"(xres)
      : "v"(px0), "v"(px1), "v"(ph0), "v"(ph1), "v"(pxr)
      : "memory");

    floatx4 acc[4][2];
#pragma unroll
    for (int ct = 0; ct < 4; ++ct) { acc[ct][0] = {0,0,0,0}; acc[ct][1] = {0,0,0,0}; }
#pragma unroll
    for (int ct = 0; ct < 4; ++ct) {
      acc[ct][0] = mfma16(x0a, wx[ct][0], acc[ct][0]);
      acc[ct][1] = mfma16(x1a, wx[ct][0], acc[ct][1]);
      acc[ct][0] = mfma16(h0a, wh[ct][0], acc[ct][0]);
      acc[ct][1] = mfma16(h1a, wh[ct][0], acc[ct][1]);
      acc[ct][0] = mfma16(x0b, wx[ct][1], acc[ct][0]);
      acc[ct][1] = mfma16(x1b, wx[ct][1], acc[ct][1]);
      acc[ct][0] = mfma16(h0b, wh[ct][1], acc[ct][0]);
      acc[ct][1] = mfma16(h1b, wh[ct][1], acc[ct][1]);
      acc[ct][0] = mfma16(x0c, wx[ct][2], acc[ct][0]);
      acc[ct][1] = mfma16(x1c, wx[ct][2], acc[ct][1]);
      acc[ct][0] = mfma16(h0c, wh[ct][2], acc[ct][0]);
      acc[ct][1] = mfma16(h1c, wh[ct][2], acc[ct][1]);
      acc[ct][0] = mfma16(x0d, wx[ct][3], acc[ct][0]);
      acc[ct][1] = mfma16(x1d, wx[ct][3], acc[ct][1]);
      acc[ct][0] = mfma16(h0d, wh[ct][3], acc[ct][0]);
      acc[ct][1] = mfma16(h1d, wh[ct][3], acc[ct][1]);
    }

    // ---- split-K reduce (single pass, 8 waves) ----
#pragma unroll
    for (int ct = 0; ct < 4; ++ct)
#pragma unroll
      for (int rt = 0; rt < 2; ++rt)
#pragma unroll
        for (int r = 0; r < 4; ++r)
          red[q][rt * 16 + hi * 4 + r][ct * 16 + lo] = acc[ct][rt][r];
    __syncthreads();

    float gacc[4] = {0.f, 0.f, 0.f, 0.f};
#pragma unroll
    for (int qq = 0; qq < 8; ++qq)
#pragma unroll
      for (int g = 0; g < 4; ++g)
        gacc[g] += red[qq][b][g * 16 + u];

    // ---- LSTM cell ----
    const float ig = gacc[0] + bias_g[0];
    const float fg = gacc[1] + bias_g[1];
    const float gg = gacc[2] + bias_g[2];
    const float og = gacc[3] + bias_g[3];
    const float si = 1.f / (1.f + __expf(-ig));
    const float sf = 1.f / (1.f + __expf(-fg));
    const float so = 1.f / (1.f + __expf(-og));
    const float tg = 1.f - 2.f / (__expf(2.f * gg) + 1.f);
    const float cn = sf * c_reg + si * tg;
    const float hn = so * (1.f - 2.f / (__expf(2.f * cn) + 1.f));
    c_reg = cn;

    const float xval = bf2f((unsigned short)xres);
    const unsigned hbf = f2bf(hn);
    const unsigned rbf = f2bf(hn + xval);
    const unsigned hpk = hbf | (((unsigned)__shfl_xor((int)hbf, 1)) << 16);
    const unsigned rpk = rbf | (((unsigned)__shfl_xor((int)rbf, 1)) << 16);

    unsigned short* HBw = HBT + ((size_t)(t + 1) * LAYERS + l) * BH;
    unsigned short* RESw = RES + ((size_t)l * SEQT + t) * BH;
    const size_t hidx = (size_t)b * HID + j0 + u;
    if (!(tid & 1)) {
      __hip_atomic_store((unsigned*)(HBw + hidx), hpk,
                         __ATOMIC_RELAXED, __HIP_MEMORY_SCOPE_AGENT);
      __hip_atomic_store((unsigned*)(RESw + hidx), rpk,
                         __ATOMIC_RELAXED, __HIP_MEMORY_SCOPE_AGENT);
    }
    if (t == SEQT - 1) {
      out[LOGITS_N + (size_t)l * BH + hidx] = hn;            // hT
      out[LOGITS_N + 131072ul + (size_t)l * BH + hidx] = cn; // cT
    }

    // ---- publish: drain stores, wg barrier, one flag store ----
    asm volatile("s_waitcnt vmcnt(0)" ::: "memory");
    __syncthreads();
    if (tid == 0)
      __hip_atomic_store(fown, (unsigned)(t + 1),
                         __ATOMIC_RELAXED, __HIP_MEMORY_SCOPE_AGENT);
  }
}

// ---------------- classifier GEMM (global_load_lds staging) ----------------
// Staging now uses __builtin_amdgcn_global_load_lds width=16: linear LDS dest
// (wave-uniform base + lane*16) with PRE-SWIZZLED global source chunk
// (cs = c8 ^ (row&7)) — produces the same swizzled LDS content as before, so
// the conflict-free XOR read side is unchanged (m201 both-sides pattern).
// Removes the VGPR round-trip (m151: +35% at 128^2). 4 blocks/CU.

__global__ __launch_bounds__(256, 4) void k_cls(
    const unsigned short* __restrict__ A, const unsigned short* __restrict__ Bw,
    const float* __restrict__ bias, float* __restrict__ out) {
  __shared__ unsigned short lds_s[2][128 * 64];   // 32 KB: staging + f32 epilogue
  unsigned short* lA = lds_s[0];
  unsigned short* lB = lds_s[1];
  const int ntile = blockIdx.x >> 5;
  const int mtile = blockIdx.x & 31;
  const int m0 = mtile << 7, n0 = ntile << 7;
  const int tid = threadIdx.x;
  const int w = tid >> 6, lane = tid & 63, lo = lane & 15, hi = lane >> 4;
  const int mw = (w >> 1) << 6, nw = (w & 1) << 6;
  const int wbase = (w << 6) << 3;                // wave-uniform LDS chunk base (shorts)

  floatx4 acc[4][4];
#pragma unroll
  for (int i = 0; i < 4; ++i)
#pragma unroll
    for (int j = 0; j < 4; ++j) acc[i][j] = {0.f, 0.f, 0.f, 0.f};

  for (int k0 = 0; k0 < HID; k0 += 64) {
#pragma unroll
    for (int qq = 0; qq < 4; ++qq) {
      const int e = qq * 256 + tid;
      const int row = e >> 3, c8 = e & 7;
      const int cs = (c8 ^ (row & 7)) << 3;       // pre-swizzled source chunk
      const unsigned short* ga = A  + (size_t)(m0 + row) * HID + k0 + cs;
      const unsigned short* gb = Bw + (size_t)(n0 + row) * HID + k0 + cs;
      unsigned short* la = lA + qq * 2048 + wbase;  // linear dest, wave-uniform
      unsigned short* lb = lB + qq * 2048 + wbase;
      __builtin_amdgcn_global_load_lds(
          (const __attribute__((address_space(1))) unsigned*)(const void*)ga,
          (__attribute__((address_space(3))) unsigned*)(void*)la, 16, 0, 0);
      __builtin_amdgcn_global_load_lds(
          (const __attribute__((address_space(1))) unsigned*)(const void*)gb,
          (__attribute__((address_space(3))) unsigned*)(void*)lb, 16, 0, 0);
    }
    __syncthreads();
#pragma unroll
    for (int kk = 0; kk < 2; ++kk) {
      short8 af[4], bfr[4];
#pragma unroll
      for (int x = 0; x < 4; ++x) {
        const int ra = mw + x * 16 + lo;
        af[x]  = *(const short8*)(lA + ra * 64 + ((((kk << 2) + hi) ^ (ra & 7)) << 3));
        const int rb = nw + x * 16 + lo;
        bfr[x] = *(const short8*)(lB + rb * 64 + ((((kk << 2) + hi) ^ (rb & 7)) << 3));
      }
#pragma unroll
      for (int mi = 0; mi < 4; ++mi)
#pragma unroll
        for (int ni = 0; ni < 4; ++ni)
          acc[mi][ni] = mfma16(af[mi], bfr[ni], acc[mi][ni]);
    }
    __syncthreads();
  }

  // ---- epilogue: two 64-row halves through LDS, 512B-coalesced row writes ----
  float* ldsf = (float*)lds_s;            // 64 x 128 f32 = 32 KB
  const int rl = tid >> 5;                // 0..7
  const int c4 = (tid & 31) << 2;         // 0..124
#pragma unroll
  for (int h = 0; h < 2; ++h) {
    __syncthreads();
    if ((mw >> 6) == h) {                 // waves owning this half stage their accs
#pragma unroll
      for (int mi = 0; mi < 4; ++mi)
#pragma unroll
        for (int ni = 0; ni < 4; ++ni)
#pragma unroll
          for (int r = 0; r < 4; ++r)
            ldsf[(mi * 16 + hi * 4 + r) * 128 + nw + ni * 16 + lo] = acc[mi][ni][r];
    }
    __syncthreads();
#pragma unroll
    for (int it = 0; it < 8; ++it) {
      const int lr = it * 8 + rl;                      // local row 0..63
      const int ra = m0 + h * 64 + lr;                 // A row = t*32+b
      const int orow = (ra & 31) * SEQT + (ra >> 5);   // out row = b*128+t
      const int v = n0 + c4;
      float4 vv = *(float4*)&ldsf[lr * 128 + c4];
      const float4 bb = *(const float4*)&bias[v];
      vv.x += bb.x; vv.y += bb.y; vv.z += bb.z; vv.w += bb.w;
      *(float4*)&out[(size_t)orow * VOCAB + v] = vv;
    }
  }
}

// ---------------- launch ----------------

extern "C" void kernel_launch(void* const* d_in, const int* in_sizes, int n_in,
                              void* d_out, int out_size, void* d_ws, size_t ws_size,
                              hipStream_t stream) {
  (void)in_sizes; (void)n_in; (void)out_size; (void)ws_size;
  const int*   tok  = (const int*)d_in[0];
  const float* h0   = (const float*)d_in[1];
  const float* c0   = (const float*)d_in[2];
  const float* emb  = (const float*)d_in[3];
  const float* wih  = (const float*)d_in[4];
  const float* whh  = (const float*)d_in[5];
  const float* bih  = (const float*)d_in[6];
  const float* bhh  = (const float*)d_in[7];
  const float* clsw = (const float*)d_in[8];
  const float* clsb = (const float*)d_in[9];
  float* out = (float*)d_out;
  char* ws = (char*)d_ws;

  unsigned short* Cls = (unsigned short*)(ws + CLS_OFF);
  unsigned short* X   = (unsigned short*)(ws + X_OFF);
  unsigned short* RES = (unsigned short*)(ws + RES_OFF);
  unsigned short* HBT = (unsigned short*)(ws + HBT_OFF);
  float*          CF  = (float*)(ws + CF_OFF);
  unsigned*       SY  = (unsigned*)(ws + SYNC_OFF);

  hipLaunchKernelGGL(k_convert, dim3(2048), dim3(256), 0, stream, clsw, Cls);
  hipLaunchKernelGGL(k_embed,   dim3(SEQT * BATCH), dim3(256), 0, stream, tok, emb, X);
  hipLaunchKernelGGL(k_init,    dim3(512), dim3(256), 0, stream, h0, c0, HBT, CF, SY);

  {
    const float* a0 = wih; const float* a1 = whh; const float* a2 = bih; const float* a3 = bhh;
    const unsigned short* a4 = X; unsigned short* a5 = RES; unsigned short* a6 = HBT;
    const float* a7 = CF; float* a8 = out; unsigned* a9 = SY;
    void* kargs[] = {&a0, &a1, &a2, &a3, &a4, &a5, &a6, &a7, &a8, &a9};
    hipLaunchCooperativeKernel((void*)k_lstm, dim3(256), dim3(512), kargs, 0, stream);
  }

  hipLaunchKernelGGL(k_cls, dim3(250 * 32), dim3(256), 0, stream,
                     RES + (size_t)3 * SEQT * BATCH * HID, Cls, clsb, out);
}

// Round 14
// 1280.355 us; speedup vs baseline: 1.1920x; 1.1920x over previous
//
#include <hip/hip_runtime.h>
#include <stdint.h>

#define LAYERS 4
#define BATCH  32
#define SEQT   128
#define HID    1024
#define VOCAB  32000

typedef __attribute__((ext_vector_type(8))) short short8;
typedef __attribute__((ext_vector_type(8))) __bf16 bf16x8;
typedef __attribute__((ext_vector_type(4))) float floatx4;

// ws layout (bytes)
#define CLS_OFF  0ul           // 32000*1024*2  = 65,536,000
#define X_OFF    65536000ul    // 128*32*1024*2 =  8,388,608
#define RES_OFF  73924608ul    // 4*128*32*1024*2 = 33,554,432
#define HBT_OFF  107479040ul   // 129*4*32*1024*2 = 33,816,576 (time-indexed h)
#define CF_OFF   141295616ul   // 4*32*1024*4   = 524,288
#define SYNC_OFF 141819904ul   // flags[l][wg] u32 at ((l*64+wg)*4) — 16B spacing

#define LOGITS_N 131072000ul
#define BH (BATCH * HID)

__device__ __forceinline__ unsigned short f2bf(float f) {
  union { float f; unsigned u; } v; v.f = f;
  unsigned r = v.u + 0x7FFF + ((v.u >> 16) & 1);
  return (unsigned short)(r >> 16);
}
__device__ __forceinline__ float bf2f(unsigned short b) {
  union { unsigned u; float f; } v; v.u = ((unsigned)b) << 16;
  return v.f;
}
__device__ __forceinline__ floatx4 mfma16(short8 a, short8 b, floatx4 c) {
  return __builtin_amdgcn_mfma_f32_16x16x32_bf16(
      __builtin_bit_cast(bf16x8, a), __builtin_bit_cast(bf16x8, b), c, 0, 0, 0);
}
__device__ __forceinline__ short8 cvt8(float4 a, float4 b) {
  short8 r;
  r[0] = (short)f2bf(a.x); r[1] = (short)f2bf(a.y);
  r[2] = (short)f2bf(a.z); r[3] = (short)f2bf(a.w);
  r[4] = (short)f2bf(b.x); r[5] = (short)f2bf(b.y);
  r[6] = (short)f2bf(b.z); r[7] = (short)f2bf(b.w);
  return r;
}

// ---------------- prep kernels ----------------

__global__ void k_convert(const float* __restrict__ clsw, unsigned short* __restrict__ oC) {
  const long long NC4 = 8192000LL;   // V*H/4
  for (long long i = (long long)blockIdx.x * blockDim.x + threadIdx.x; i < NC4;
       i += (long long)gridDim.x * blockDim.x) {
    float4 v = *(const float4*)(clsw + (i << 2));
    ushort4 o; o.x = f2bf(v.x); o.y = f2bf(v.y); o.z = f2bf(v.z); o.w = f2bf(v.w);
    *(ushort4*)(oC + (i << 2)) = o;
  }
}

__global__ void k_embed(const int* __restrict__ tok, const float* __restrict__ emb,
                        unsigned short* __restrict__ X) {
  const int bt = blockIdx.x;            // t*32 + b
  const int t = bt >> 5, b = bt & 31;
  const int v = tok[b * SEQT + t];      // dec_input is [B,T]
  const float4* src = (const float4*)(emb + (size_t)v * HID);
  ushort4* dst = (ushort4*)(X + (size_t)bt * HID);
  const int i = threadIdx.x;
  float4 f = src[i];
  ushort4 o; o.x = f2bf(f.x); o.y = f2bf(f.y); o.z = f2bf(f.z); o.w = f2bf(f.w);
  dst[i] = o;
}

__global__ void k_init(const float* __restrict__ h0, const float* __restrict__ c0,
                       unsigned short* __restrict__ HBT, float* __restrict__ CF,
                       unsigned* __restrict__ sync) {
  const int i = blockIdx.x * blockDim.x + threadIdx.x;
  if (i < 4096) sync[i] = 0u;
  if (i < LAYERS * BATCH * HID) {
    HBT[i] = f2bf(h0[i]);   // HBT[t=0][l][b][h] == h0 layout
    CF[i] = c0[i];
  }
}

// ---------------- persistent LSTM (round-7/12 verified structure, 883 us) ----------------

__global__ __launch_bounds__(512, 2) void k_lstm(
    const float* __restrict__ Wih, const float* __restrict__ Whh,
    const float* __restrict__ bih, const float* __restrict__ bhh,
    const unsigned short* __restrict__ X, unsigned short* __restrict__ RES,
    unsigned short* __restrict__ HBT, const float* __restrict__ CF,
    float* __restrict__ out, unsigned* __restrict__ syncp) {
  const int p = blockIdx.x;
  const int l = (p & 7) >> 1;                       // XCD pair {2l,2l+1}
  const int jj = ((p >> 3) << 1) | (p & 1);         // 0..63 within layer
  const int j0 = jj << 4;
  const int tid = threadIdx.x;
  const int q = tid >> 6;                 // wave 0..7 -> K slice q*128
  const int lane = tid & 63;
  const int lo = lane & 15, hi = lane >> 4;
  const int u = tid & 15, b = tid >> 4;   // cell mapping: unit u (fast), batch b

  __shared__ float red[8][32][66];        // split-K reduce, padded
  __shared__ unsigned mbx, mbh;           // LDS mailboxes

  if (tid == 0) { mbx = 0u; mbh = 0u; }

  // one-time acquire: invalidate L1/L2 (stale lines from prior replay / poison)
  (void)__hip_atomic_load(syncp + 2048, __ATOMIC_ACQUIRE, __HIP_MEMORY_SCOPE_AGENT);

  const unsigned* fx = syncp + (((l - 1) & 3) * 64 + lane) * 4;
  const unsigned* fh = syncp + (l * 64 + lane) * 4;
  unsigned* fown = syncp + (l * 64 + jj) * 4;

  // ---- one-time: weights f32 -> bf16 fragments in registers ----
  short8 wx[4][4], wh[4][4];              // [gate][ks], 128 regs
  {
    const size_t lb = (size_t)l * 4096;
#pragma unroll
    for (int ct = 0; ct < 4; ++ct) {
#pragma unroll
      for (int ks = 0; ks < 4; ++ks) {
        const size_t off = (lb + (size_t)(ct * 1024 + j0 + lo)) * HID
                         + (size_t)q * 128 + ks * 32 + hi * 8;
        float4 a0 = *(const float4*)(Wih + off);
        float4 a1 = *(const float4*)(Wih + off + 4);
        wx[ct][ks] = cvt8(a0, a1);
        float4 b0 = *(const float4*)(Whh + off);
        float4 b1 = *(const float4*)(Whh + off + 4);
        wh[ct][ks] = cvt8(b0, b1);
      }
    }
  }
  float bias_g[4];
#pragma unroll
  for (int g = 0; g < 4; ++g)
    bias_g[g] = bih[l * 4096 + g * 1024 + j0 + u] + bhh[l * 4096 + g * 1024 + j0 + u];
  float c_reg = CF[(size_t)l * BH + (size_t)b * HID + j0 + u];

  __syncthreads();   // mailbox init visible

  for (int t = 0; t < SEQT; ++t) {
    // ---- x gate: wave0 polls layer l-1 flags, others spin LDS mailbox ----
    if (q == 0) {
      if (l > 0) {
        for (;;) {
          int ok = (__hip_atomic_load(fx, __ATOMIC_RELAXED, __HIP_MEMORY_SCOPE_AGENT)
                    >= (unsigned)(t + 1));
          if (__all(ok)) break;
          __builtin_amdgcn_s_sleep(1);
        }
      }
      __hip_atomic_store(&mbx, (unsigned)(t + 1),
                         __ATOMIC_RELAXED, __HIP_MEMORY_SCOPE_WORKGROUP);
    } else {
      while (__hip_atomic_load(&mbx, __ATOMIC_RELAXED, __HIP_MEMORY_SCOPE_WORKGROUP)
             < (unsigned)(t + 1))
        __builtin_amdgcn_s_sleep(1);
    }

    const unsigned short* xsrc = (l == 0)
        ? (X + (size_t)t * BH)
        : (RES + ((size_t)(l - 1) * SEQT + t) * BH);

    // ---- x phase: cached loads + 16 x-MFMAs (overlaps the h wait) ----
    const unsigned short* px0 = xsrc + (size_t)lo * HID + q * 128 + hi * 8;
    const unsigned short* px1 = px0 + 16 * HID;
    const unsigned short* pxr = xsrc + (size_t)b * HID + j0 + u;

    short8 x0a, x0b, x0c, x0d, x1a, x1b, x1c, x1d;
    unsigned xres;
    asm volatile(
      "global_load_dwordx4 %0, %9,  off\n\t"
      "global_load_dwordx4 %1, %9,  off offset:64\n\t"
      "global_load_dwordx4 %2, %9,  off offset:128\n\t"
      "global_load_dwordx4 %3, %9,  off offset:192\n\t"
      "global_load_dwordx4 %4, %10, off\n\t"
      "global_load_dwordx4 %5, %10, off offset:64\n\t"
      "global_load_dwordx4 %6, %10, off offset:128\n\t"
      "global_load_dwordx4 %7, %10, off offset:192\n\t"
      "global_load_ushort  %8, %11, off\n\t"
      "s_waitcnt vmcnt(0)"
      : "=&v"(x0a), "=&v"(x0b), "=&v"(x0c), "=&v"(x0d),
        "=&v"(x1a), "=&v"(x1b), "=&v"(x1c), "=&v"(x1d), "=&v"(xres)
      : "v"(px0), "v"(px1), "v"(pxr)
      : "memory");

    floatx4 acc[4][2];
#pragma unroll
    for (int ct = 0; ct < 4; ++ct) { acc[ct][0] = {0,0,0,0}; acc[ct][1] = {0,0,0,0}; }
#pragma unroll
    for (int ct = 0; ct < 4; ++ct) {
      acc[ct][0] = mfma16(x0a, wx[ct][0], acc[ct][0]);
      acc[ct][1] = mfma16(x1a, wx[ct][0], acc[ct][1]);
      acc[ct][0] = mfma16(x0b, wx[ct][1], acc[ct][0]);
      acc[ct][1] = mfma16(x1b, wx[ct][1], acc[ct][1]);
      acc[ct][0] = mfma16(x0c, wx[ct][2], acc[ct][0]);
      acc[ct][1] = mfma16(x1c, wx[ct][2], acc[ct][1]);
      acc[ct][0] = mfma16(x0d, wx[ct][3], acc[ct][0]);
      acc[ct][1] = mfma16(x1d, wx[ct][3], acc[ct][1]);
    }

    // ---- h gate ----
    if (q == 0) {
      if (t > 0) {
        for (;;) {
          int ok = (__hip_atomic_load(fh, __ATOMIC_RELAXED, __HIP_MEMORY_SCOPE_AGENT)
                    >= (unsigned)t);
          if (__all(ok)) break;
          __builtin_amdgcn_s_sleep(1);
        }
      }
      __hip_atomic_store(&mbh, (unsigned)(t + 1),
                         __ATOMIC_RELAXED, __HIP_MEMORY_SCOPE_WORKGROUP);
    } else {
      while (__hip_atomic_load(&mbh, __ATOMIC_RELAXED, __HIP_MEMORY_SCOPE_WORKGROUP)
             < (unsigned)(t + 1))
        __builtin_amdgcn_s_sleep(1);
    }

    // ---- h phase: cached loads (write-once HBT[t]) + 16 h-MFMAs ----
    const unsigned short* hsrc = HBT + ((size_t)t * LAYERS + l) * BH;
    const unsigned short* ph0 = hsrc + (size_t)lo * HID + q * 128 + hi * 8;
    const unsigned short* ph1 = ph0 + 16 * HID;

    short8 h0a, h0b, h0c, h0d, h1a, h1b, h1c, h1d;
    asm volatile(
      "global_load_dwordx4 %0, %8, off\n\t"
      "global_load_dwordx4 %1, %8, off offset:64\n\t"
      "global_load_dwordx4 %2, %8, off offset:128\n\t"
      "global_load_dwordx4 %3, %8, off offset:192\n\t"
      "global_load_dwordx4 %4, %9, off\n\t"
      "global_load_dwordx4 %5, %9, off offset:64\n\t"
      "global_load_dwordx4 %6, %9, off offset:128\n\t"
      "global_load_dwordx4 %7, %9, off offset:192\n\t"
      "s_waitcnt vmcnt(0)"
      : "=&v"(h0a), "=&v"(h0b), "=&v"(h0c), "=&v"(h0d),
        "=&v"(h1a), "=&v"(h1b), "=&v"(h1c), "=&v"(h1d)
      : "v"(ph0), "v"(ph1)
      : "memory");

#pragma unroll
    for (int ct = 0; ct < 4; ++ct) {
      acc[ct][0] = mfma16(h0a, wh[ct][0], acc[ct][0]);
      acc[ct][1] = mfma16(h1a, wh[ct][0], acc[ct][1]);
      acc[ct][0] = mfma16(h0b, wh[ct][1], acc[ct][0]);
      acc[ct][1] = mfma16(h1b, wh[ct][1], acc[ct][1]);
      acc[ct][0] = mfma16(h0c, wh[ct][2], acc[ct][0]);
      acc[ct][1] = mfma16(h1c, wh[ct][2], acc[ct][1]);
      acc[ct][0] = mfma16(h0d, wh[ct][3], acc[ct][0]);
      acc[ct][1] = mfma16(h1d, wh[ct][3], acc[ct][1]);
    }

    // ---- split-K reduce (single pass, 8 waves) ----
#pragma unroll
    for (int ct = 0; ct < 4; ++ct)
#pragma unroll
      for (int rt = 0; rt < 2; ++rt)
#pragma unroll
        for (int r = 0; r < 4; ++r)
          red[q][rt * 16 + hi * 4 + r][ct * 16 + lo] = acc[ct][rt][r];
    __syncthreads();

    float gacc[4] = {0.f, 0.f, 0.f, 0.f};
#pragma unroll
    for (int qq = 0; qq < 8; ++qq)
#pragma unroll
      for (int g = 0; g < 4; ++g)
        gacc[g] += red[qq][b][g * 16 + u];

    // ---- LSTM cell ----
    const float ig = gacc[0] + bias_g[0];
    const float fg = gacc[1] + bias_g[1];
    const float gg = gacc[2] + bias_g[2];
    const float og = gacc[3] + bias_g[3];
    const float si = 1.f / (1.f + __expf(-ig));
    const float sf = 1.f / (1.f + __expf(-fg));
    const float so = 1.f / (1.f + __expf(-og));
    const float tg = 1.f - 2.f / (__expf(2.f * gg) + 1.f);
    const float cn = sf * c_reg + si * tg;
    const float hn = so * (1.f - 2.f / (__expf(2.f * cn) + 1.f));
    c_reg = cn;

    const float xval = bf2f((unsigned short)xres);
    const unsigned hbf = f2bf(hn);
    const unsigned rbf = f2bf(hn + xval);
    const unsigned hpk = hbf | (((unsigned)__shfl_xor((int)hbf, 1)) << 16);
    const unsigned rpk = rbf | (((unsigned)__shfl_xor((int)rbf, 1)) << 16);

    unsigned short* HBw = HBT + ((size_t)(t + 1) * LAYERS + l) * BH;
    unsigned short* RESw = RES + ((size_t)l * SEQT + t) * BH;
    const size_t hidx = (size_t)b * HID + j0 + u;
    if (!(tid & 1)) {
      __hip_atomic_store((unsigned*)(HBw + hidx), hpk,
                         __ATOMIC_RELAXED, __HIP_MEMORY_SCOPE_AGENT);
      __hip_atomic_store((unsigned*)(RESw + hidx), rpk,
                         __ATOMIC_RELAXED, __HIP_MEMORY_SCOPE_AGENT);
    }
    if (t == SEQT - 1) {
      out[LOGITS_N + (size_t)l * BH + hidx] = hn;            // hT
      out[LOGITS_N + 131072ul + (size_t)l * BH + hidx] = cn; // cT
    }

    // ---- publish: drain stores, wg barrier, one flag store ----
    asm volatile("s_waitcnt vmcnt(0)" ::: "memory");
    __syncthreads();
    if (tid == 0)
      __hip_atomic_store(fown, (unsigned)(t + 1),
                         __ATOMIC_RELAXED, __HIP_MEMORY_SCOPE_AGENT);
  }
}

// ---------------- classifier GEMM (double-buffered async prefetch) ----------------
// LDS = 2 bufs x (lA+lB). Each iteration: issue next-tile global_load_lds FIRST
// (linear dest + pre-swizzled source, both-sides pattern), then s_waitcnt vmcnt(8)
// (counted: waits only the current buffer's 8 loads, leaves the 8 new in flight),
// RAW s_barrier (no compiler vmcnt(0) drain), compute, raw barrier. Staging
// latency hides under MFMA. Epilogue: r12's verified coalesced LDS-transpose.

__global__ __launch_bounds__(256, 2) void k_cls(
    const unsigned short* __restrict__ A, const unsigned short* __restrict__ Bw,
    const float* __restrict__ bias, float* __restrict__ out) {
  __shared__ unsigned short lds_s[2][2][128 * 64];   // [buf][mat] 64 KB
  const int ntile = blockIdx.x >> 5;
  const int mtile = blockIdx.x & 31;
  const int m0 = mtile << 7, n0 = ntile << 7;
  const int tid = threadIdx.x;
  const int w = tid >> 6, lane = tid & 63, lo = lane & 15, hi = lane >> 4;
  const int mw = (w >> 1) << 6, nw = (w & 1) << 6;
  const int wbase = w << 9;                 // wave-uniform LDS chunk base (shorts)

  floatx4 acc[4][4];
#pragma unroll
  for (int i = 0; i < 4; ++i)
#pragma unroll
    for (int j = 0; j < 4; ++j) acc[i][j] = {0.f, 0.f, 0.f, 0.f};

  auto stage = [&](int buf, int k0) {
#pragma unroll
    for (int qq = 0; qq < 4; ++qq) {
      const int e = qq * 256 + tid;
      const int row = e >> 3, c8 = e & 7;
      const int cs = (c8 ^ (row & 7)) << 3;       // pre-swizzled source chunk
      const unsigned short* ga = A  + (size_t)(m0 + row) * HID + k0 + cs;
      const unsigned short* gb = Bw + (size_t)(n0 + row) * HID + k0 + cs;
      unsigned short* la = &lds_s[buf][0][0] + qq * 2048 + wbase;
      unsigned short* lb = &lds_s[buf][1][0] + qq * 2048 + wbase;
      __builtin_amdgcn_global_load_lds(
          (const __attribute__((address_space(1))) unsigned*)(const void*)ga,
          (__attribute__((address_space(3))) unsigned*)(void*)la, 16, 0, 0);
      __builtin_amdgcn_global_load_lds(
          (const __attribute__((address_space(1))) unsigned*)(const void*)gb,
          (__attribute__((address_space(3))) unsigned*)(void*)lb, 16, 0, 0);
    }
  };

  stage(0, 0);                                // prologue
  for (int it = 0; it < 16; ++it) {
    const int cur = it & 1;
    if (it < 15) {
      stage(cur ^ 1, (it + 1) << 6);          // issue next tile (8 loads)
      asm volatile("s_waitcnt vmcnt(8)" ::: "memory");   // current buf ready
    } else {
      asm volatile("s_waitcnt vmcnt(0)" ::: "memory");
    }
    __builtin_amdgcn_s_barrier();             // all waves' current stores landed
    asm volatile("" ::: "memory");
    const unsigned short* lA = &lds_s[cur][0][0];
    const unsigned short* lB = &lds_s[cur][1][0];
#pragma unroll
    for (int kk = 0; kk < 2; ++kk) {
      short8 af[4], bfr[4];
#pragma unroll
      for (int x = 0; x < 4; ++x) {
        const int ra = mw + x * 16 + lo;
        af[x]  = *(const short8*)(lA + ra * 64 + ((((kk << 2) + hi) ^ (ra & 7)) << 3));
        const int rb = nw + x * 16 + lo;
        bfr[x] = *(const short8*)(lB + rb * 64 + ((((kk << 2) + hi) ^ (rb & 7)) << 3));
      }
#pragma unroll
      for (int mi = 0; mi < 4; ++mi)
#pragma unroll
        for (int ni = 0; ni < 4; ++ni)
          acc[mi][ni] = mfma16(af[mi], bfr[ni], acc[mi][ni]);
    }
    asm volatile("" ::: "memory");
    __builtin_amdgcn_s_barrier();             // compute done before overwrite
  }

  // ---- epilogue: two 64-row halves through LDS, 512B-coalesced row writes ----
  float* ldsf = (float*)lds_s;            // 64 x 128 f32 = 32 KB
  const int rl = tid >> 5;                // 0..7
  const int c4 = (tid & 31) << 2;         // 0..124
#pragma unroll
  for (int h = 0; h < 2; ++h) {
    __syncthreads();
    if ((mw >> 6) == h) {                 // waves owning this half stage their accs
#pragma unroll
      for (int mi = 0; mi < 4; ++mi)
#pragma unroll
        for (int ni = 0; ni < 4; ++ni)
#pragma unroll
          for (int r = 0; r < 4; ++r)
            ldsf[(mi * 16 + hi * 4 + r) * 128 + nw + ni * 16 + lo] = acc[mi][ni][r];
    }
    __syncthreads();
#pragma unroll
    for (int it = 0; it < 8; ++it) {
      const int lr = it * 8 + rl;                      // local row 0..63
      const int ra = m0 + h * 64 + lr;                 // A row = t*32+b
      const int orow = (ra & 31) * SEQT + (ra >> 5);   // out row = b*128+t
      const int v = n0 + c4;
      float4 vv = *(float4*)&ldsf[lr * 128 + c4];
      const float4 bb = *(const float4*)&bias[v];
      vv.x += bb.x; vv.y += bb.y; vv.z += bb.z; vv.w += bb.w;
      *(float4*)&out[(size_t)orow * VOCAB + v] = vv;
    }
  }
}

// ---------------- launch ----------------

extern "C" void kernel_launch(void* const* d_in, const int* in_sizes, int n_in,
                              void* d_out, int out_size, void* d_ws, size_t ws_size,
                              hipStream_t stream) {
  (void)in_sizes; (void)n_in; (void)out_size; (void)ws_size;
  const int*   tok  = (const int*)d_in[0];
  const float* h0   = (const float*)d_in[1];
  const float* c0   = (const float*)d_in[2];
  const float* emb  = (const float*)d_in[3];
  const float* wih  = (const float*)d_in[4];
  const float* whh  = (const float*)d_in[5];
  const float* bih  = (const float*)d_in[6];
  const float* bhh  = (const float*)d_in[7];
  const float* clsw = (const float*)d_in[8];
  const float* clsb = (const float*)d_in[9];
  float* out = (float*)d_out;
  char* ws = (char*)d_ws;

  unsigned short* Cls = (unsigned short*)(ws + CLS_OFF);
  unsigned short* X   = (unsigned short*)(ws + X_OFF);
  unsigned short* RES = (unsigned short*)(ws + RES_OFF);
  unsigned short* HBT = (unsigned short*)(ws + HBT_OFF);
  float*          CF  = (float*)(ws + CF_OFF);
  unsigned*       SY  = (unsigned*)(ws + SYNC_OFF);

  hipLaunchKernelGGL(k_convert, dim3(2048), dim3(256), 0, stream, clsw, Cls);
  hipLaunchKernelGGL(k_embed,   dim3(SEQT * BATCH), dim3(256), 0, stream, tok, emb, X);
  hipLaunchKernelGGL(k_init,    dim3(512), dim3(256), 0, stream, h0, c0, HBT, CF, SY);

  {
    const float* a0 = wih; const float* a1 = whh; const float* a2 = bih; const float* a3 = bhh;
    const unsigned short* a4 = X; unsigned short* a5 = RES; unsigned short* a6 = HBT;
    const float* a7 = CF; float* a8 = out; unsigned* a9 = SY;
    void* kargs[] = {&a0, &a1, &a2, &a3, &a4, &a5, &a6, &a7, &a8, &a9};
    hipLaunchCooperativeKernel((void*)k_lstm, dim3(256), dim3(512), kargs, 0, stream);
  }

  hipLaunchKernelGGL(k_cls, dim3(250 * 32), dim3(256), 0, stream,
                     RES + (size_t)3 * SEQT * BATCH * HID, Cls, clsb, out);
}